// Round 7
// baseline (1765.723 us; speedup 1.0000x reference)
//
#include <hip/hip_runtime.h>

// Elman RNN, B=256,T=256,I=128,H=512,O=1.
// R7: 4-way H-split. 64 blocks = 16 batch-groups x 4 members; block (g,m)
// owns rows [16g,16g+16) and h-cols [128m,128m+128). Its W_hh slice
// (512x128 bf16 = 128 KB) lives ENTIRELY in LDS; W_ih slice = 16 VGPR/wave.
// Zero W streaming (R2/R5/R6 proved the 128-VGPR cap is immovable and the
// per-CU L2 W-stream ~48 B/cyc was the wall at ~4.8 us/step).
// Per step: 20 MFMAs/wave -> h slice; exchange slices among the 4 group peers
// via double-buffered global frag buffer + monotonic flags (release/acquire,
// agent scope). Deadlock-free: 64 blocks all co-resident (<=256 CUs, 1/CU by
// LDS). Group's 4 blocks land on one XCD under the bid&7 heuristic (perf only).

#define T_   256
#define I_   128
#define H_   512
#define RS   648     // a_lds row stride in ushorts (640 + 8 pad)
#define NT_TOT 32
#define NKC_HH 16
#define NKC_IH 4

// d_ws layout (ushort elements)
#define HH_ELEMS (NT_TOT * NKC_HH * 64 * 8)        // 262144  (512 KB)
#define IH_OFF   HH_ELEMS
#define IH_ELEMS (NT_TOT * NKC_IH * 64 * 8)        // 65536   (128 KB)
#define HB_OFF   (IH_OFF + IH_ELEMS)               // 327680
#define HB_ELEMS (2 * 16 * 32 * 64 * 4)            // 262144  (512 KB)
#define FLAGS_BYTE_OFF ((size_t)(HB_OFF + HB_ELEMS) * 2)   // 1179648 B

typedef __attribute__((ext_vector_type(8))) short short8;
typedef __attribute__((ext_vector_type(4))) float f32x4;

static __device__ inline unsigned short f2bf(float f) {
    union { float f; unsigned u; } v; v.f = f;
    unsigned r = v.u + 0x7fffu + ((v.u >> 16) & 1u);   // RNE
    return (unsigned short)(r >> 16);
}
static __device__ inline float bf2f(unsigned short s) {
    union { unsigned u; float f; } v; v.u = ((unsigned)s) << 16;
    return v.f;
}
static __device__ inline float fast_tanh(float x) {
    float e = __expf(2.0f * x);
    return 1.0f - 2.0f / (e + 1.0f);
}

// Fragment layout: frag(nt, kc)[lane][e] = B[k][n], k = kc*32+(lane>>4)*8+e,
// n = nt*16+(lane&15). W_hh frags at [(nt*16+kc)*64+lane]*8; W_ih frags at
// IH_OFF + [(nt*4+kx)*64+lane]*8.
__global__ void pack_w(const float* __restrict__ W_ih,
                       const float* __restrict__ W_hh,
                       unsigned short* __restrict__ ws) {
    int idx = blockIdx.x * blockDim.x + threadIdx.x;   // (nt, kc, lane)
    if (idx >= NT_TOT * 20 * 64) return;
    int lane = idx & 63;
    int kc   = (idx >> 6) % 20;
    int nt   = (idx >> 6) / 20;
    int n  = nt * 16 + (lane & 15);
    int k0 = kc * 32 + (lane >> 4) * 8;
    unsigned short* dst = (kc < NKC_HH)
        ? ws + ((size_t)(nt * NKC_HH + kc) * 64 + lane) * 8
        : ws + IH_OFF + ((size_t)(nt * NKC_IH + (kc - NKC_HH)) * 64 + lane) * 8;
#pragma unroll
    for (int e = 0; e < 8; ++e) {
        int k = k0 + e;
        float v = (k < H_) ? W_hh[n * H_ + k] : W_ih[n * I_ + (k - H_)];
        dst[e] = f2bf(v);
    }
}

__global__ __launch_bounds__(512)
void rnn_main(const float* __restrict__ x,
              const unsigned short* __restrict__ ws,
              const float* __restrict__ b_ih,
              const float* __restrict__ b_hh,
              const float* __restrict__ fc_w,
              const float* __restrict__ fc_b,
              float* __restrict__ out) {
    __shared__ __align__(16) unsigned short a_lds[16 * RS];            // 20.25 KB
    __shared__ __align__(16) unsigned short w_lds[8 * NKC_HH * 64 * 8]; // 128 KB

    const int tid  = threadIdx.x;
    const int lane = tid & 63;
    const int w    = tid >> 6;          // wave 0..7 -> local n-tile
    const int q    = lane >> 4;
    const int mr   = lane & 15;

    // block -> (group, member); same-XCD grouping under bid&7 heuristic
    const int bid = blockIdx.x;
    const int xcd = bid & 7;
    const int r   = bid >> 3;           // 0..7
    const int g   = xcd * 2 + (r >> 2); // 0..15
    const int m   = r & 3;              // 0..3
    const int bb  = g * 16;             // batch row base

    const ushort4* __restrict__ hbuf4 = (const ushort4*)(ws + HB_OFF);
    ushort4* __restrict__ hbuf4w = (ushort4*)(ws + HB_OFF);
    int* __restrict__ flags = (int*)((char*)ws + FLAGS_BYTE_OFF);

    // zero A-tile (h0 = 0)
    for (int i = tid; i < 16 * RS; i += 512) a_lds[i] = 0;

    // preload this block's W_hh slice (nt in [8m, 8m+8)) into LDS: 8192 frags
    {
        const unsigned short* src = ws + (size_t)m * 8 * NKC_HH * 64 * 8;
        for (int i = tid; i < 8 * NKC_HH * 64; i += 512)
            *(short8*)&w_lds[(size_t)i * 8] = *(const short8*)(src + (size_t)i * 8);
    }

    const int nt_g = m * 8 + w;          // this wave's global n-tile
    const int colg = nt_g * 16 + mr;     // this lane's output column
    const float bias = b_ih[colg] + b_hh[colg];

    // W_ih slice frags: 4 per wave (16 VGPRs) — low pressure, stays resident
    short8 wih[NKC_IH];
#pragma unroll
    for (int kx = 0; kx < NKC_IH; ++kx)
        wih[kx] = *(const short8*)(ws + IH_OFF +
            ((size_t)(nt_g * NKC_IH + kx) * 64 + lane) * 8);

    // x staging: thread -> (row = tid>>5, 4 floats at col 4*(tid&31))
    const int xrow = tid >> 5;
    const int xc   = (tid & 31) * 4;
    const float* xbase = x + (size_t)(bb + xrow) * T_ * I_ + xc;
    float4 xreg = *(const float4*)(xbase);   // t = 0

    __syncthreads();   // a_lds zeros + w_lds visible

    for (int t = 0; t < T_; ++t) {
        // stage x_t into LDS (bf16)
        {
            ushort4 xs;
            xs.x = f2bf(xreg.x); xs.y = f2bf(xreg.y);
            xs.z = f2bf(xreg.z); xs.w = f2bf(xreg.w);
            *(ushort4*)&a_lds[xrow * RS + H_ + xc] = xs;
        }
        __syncthreads();   // x_t + full h_t visible

        if (t + 1 < T_)
            xreg = *(const float4*)(xbase + (size_t)(t + 1) * I_);

        // K-loop: 16 LDS W_hh kcs (2 accumulators to break the MFMA chain)
        f32x4 acc0 = (f32x4)(0.0f), acc1 = (f32x4)(0.0f);
#pragma unroll
        for (int kc = 0; kc < NKC_HH; kc += 2) {
            short8 af0 = *(const short8*)&a_lds[mr * RS + kc * 32 + q * 8];
            short8 af1 = *(const short8*)&a_lds[mr * RS + (kc + 1) * 32 + q * 8];
            short8 b0 = *(const short8*)&w_lds[((size_t)(w * NKC_HH + kc) * 64 + lane) * 8];
            short8 b1 = *(const short8*)&w_lds[((size_t)(w * NKC_HH + kc + 1) * 64 + lane) * 8];
            acc0 = __builtin_amdgcn_mfma_f32_16x16x32_bf16(af0, b0, acc0, 0, 0, 0);
            acc1 = __builtin_amdgcn_mfma_f32_16x16x32_bf16(af1, b1, acc1, 0, 0, 0);
        }
        // x part: 4 register-resident W_ih kcs
#pragma unroll
        for (int kx = 0; kx < NKC_IH; ++kx) {
            short8 af = *(const short8*)&a_lds[mr * RS + H_ + kx * 32 + q * 8];
            if (kx & 1) acc1 = __builtin_amdgcn_mfma_f32_16x16x32_bf16(af, wih[kx], acc1, 0, 0, 0);
            else        acc0 = __builtin_amdgcn_mfma_f32_16x16x32_bf16(af, wih[kx], acc0, 0, 0, 0);
        }
        __syncthreads();   // all reads of h_t done before overwrite

        // epilogue: h_{t+1}[rows q*4+e][colg] = tanh(acc+bias)
        const int buf = t & 1;
        {
            ushort4 hv4;
            float h0 = fast_tanh(acc0[0] + acc1[0] + bias);
            float h1 = fast_tanh(acc0[1] + acc1[1] + bias);
            float h2 = fast_tanh(acc0[2] + acc1[2] + bias);
            float h3 = fast_tanh(acc0[3] + acc1[3] + bias);
            hv4.x = f2bf(h0); hv4.y = f2bf(h1); hv4.z = f2bf(h2); hv4.w = f2bf(h3);
            a_lds[(q * 4 + 0) * RS + colg] = hv4.x;
            a_lds[(q * 4 + 1) * RS + colg] = hv4.y;
            a_lds[(q * 4 + 2) * RS + colg] = hv4.z;
            a_lds[(q * 4 + 3) * RS + colg] = hv4.w;
            // export own frags: coalesced 8B store per lane
            hbuf4w[((size_t)(buf * 16 + g) * 32 + nt_g) * 64 + lane] = hv4;
        }
        __syncthreads();   // all waves' hbuf stores drained (vmcnt) + a_lds done

        // signal + wait peers (flags monotonic: value t+1)
        if (tid == m)
            __hip_atomic_store(&flags[g * 4 + m], t + 1,
                               __ATOMIC_RELEASE, __HIP_MEMORY_SCOPE_AGENT);
        if (tid < 4 && tid != m) {
            while (__hip_atomic_load(&flags[g * 4 + tid],
                                     __ATOMIC_RELAXED, __HIP_MEMORY_SCOPE_AGENT) < t + 1)
                __builtin_amdgcn_s_sleep(1);
        }
        __syncthreads();

        // per-wave acquire (cache inv) then import 3 peer slices (12 KB)
        (void)__hip_atomic_load(&flags[g * 4], __ATOMIC_ACQUIRE, __HIP_MEMORY_SCOPE_AGENT);
#pragma unroll
        for (int it = 0; it < 3; ++it) {
            int f = tid + it * 512;          // 0..1535 over (pp, nt_local, lane)
            int pp = f >> 9;                 // 0..2
            int nl = (f >> 6) & 7;
            int ls = f & 63;
            int peer = pp + (pp >= m ? 1 : 0);
            int nt = peer * 8 + nl;
            ushort4 v = hbuf4[((size_t)(buf * 16 + g) * 32 + nt) * 64 + ls];
            int col = nt * 16 + (ls & 15);
            int r0  = (ls >> 4) * 4;
            a_lds[(r0 + 0) * RS + col] = v.x;
            a_lds[(r0 + 1) * RS + col] = v.y;
            a_lds[(r0 + 2) * RS + col] = v.z;
            a_lds[(r0 + 3) * RS + col] = v.w;
        }
        // next iteration's top barrier orders these ds_writes vs A-reads
    }
    __syncthreads();

    // out[b] = h_T[b] . fc_w + fc_b — member 0 of each group writes 16 rows
    if (m == 0) {
        const int row = tid >> 5;
        const int l32 = tid & 31;
        float s = 0.0f;
        for (int k = l32; k < H_; k += 32)
            s += bf2f(a_lds[row * RS + k]) * fc_w[k];
#pragma unroll
        for (int off = 16; off > 0; off >>= 1)
            s += __shfl_down(s, off, 32);
        if (l32 == 0) out[bb + row] = s + fc_b[0];
    }
}

extern "C" void kernel_launch(void* const* d_in, const int* in_sizes, int n_in,
                              void* d_out, int out_size, void* d_ws, size_t ws_size,
                              hipStream_t stream) {
    const float* x    = (const float*)d_in[0];
    const float* W_ih = (const float*)d_in[1];
    const float* W_hh = (const float*)d_in[2];
    const float* b_ih = (const float*)d_in[3];
    const float* b_hh = (const float*)d_in[4];
    const float* fc_w = (const float*)d_in[5];
    const float* fc_b = (const float*)d_in[6];
    unsigned short* ws = (unsigned short*)d_ws;   // needs ~1.13 MB

    // zero the flag block (harness poisons d_ws with 0xAA before every launch)
    hipMemsetAsync((char*)d_ws + FLAGS_BYTE_OFF, 0, 256, stream);
    pack_w<<<160, 256, 0, stream>>>(W_ih, W_hh, ws);
    rnn_main<<<64, 512, 0, stream>>>(x, ws, b_ih, b_hh, fc_w, fc_b, (float*)d_out);
}